// Round 2
// baseline (1665.908 us; speedup 1.0000x reference)
//
#include <hip/hip_runtime.h>
#include <hip/hip_bf16.h>
#include <cstddef>

typedef unsigned short u16;
typedef short bf16x8 __attribute__((ext_vector_type(8)));
typedef unsigned short u16x8 __attribute__((ext_vector_type(8)));
typedef float f32x4 __attribute__((ext_vector_type(4)));

constexpr int CB = 128;    // batch
constexpr int CT = 512;    // time
constexpr int CE = 128;    // embed dim
constexpr int CK = 20;     // tags

// ---- workspace layout (bytes) ----
constexpr size_t OFF_FLAG  = 0;                       // int dtype flag (1=bf16 inputs)
constexpr size_t OFF_WIH0  = 256;                     // bf16 [1024][128]
constexpr size_t OFF_WHH0  = OFF_WIH0 + 262144;       // bf16 [1024][128]
constexpr size_t OFF_WIH1  = OFF_WHH0 + 262144;       // bf16 [1024][256]
constexpr size_t OFF_WHH1  = OFF_WIH1 + 524288;       // bf16 [1024][128]
constexpr size_t OFF_WOUT  = OFF_WHH1 + 262144;       // bf16 [20][256]
constexpr size_t OFF_B0    = OFF_WOUT + 10240;        // f32 [1024]
constexpr size_t OFF_B1    = OFF_B0 + 4096;           // f32 [1024]
constexpr size_t OFF_BOUT  = OFF_B1 + 4096;           // f32 [20]
constexpr size_t OFF_TRANS = OFF_BOUT + 256;          // f32 [400]
constexpr size_t OFF_START = OFF_TRANS + 1792;        // f32 [20]
constexpr size_t OFF_END   = OFF_START + 256;         // f32 [20]
constexpr size_t OFF_PART  = OFF_END + 256;           // f32 [256]: logZ[128], score[128]
constexpr size_t OFF_X0    = 2097152;                 // bf16 [65536][128]
constexpr size_t OFF_H0    = OFF_X0 + 16777216;       // bf16 [65536][256]
constexpr size_t OFF_H1    = OFF_H0 + 33554432;       // bf16 [65536][256]
constexpr size_t OFF_EM    = OFF_H1 + 33554432;       // f32  [65536][20]
constexpr size_t OFF_Z     = OFF_EM + 5242880;        // bf16 [65536][1024] (reused L0/L1)
constexpr size_t WS_NEED   = OFF_Z + 134217728;       // ~225.4 MB

__device__ __forceinline__ float b2f(u16 u) {
    union { unsigned int i; float f; } v; v.i = ((unsigned int)u) << 16; return v.f;
}
__device__ __forceinline__ u16 f2b(float f) {
    union { float f; unsigned int i; } v; v.f = f;
    unsigned int r = v.i + 0x7FFFu + ((v.i >> 16) & 1u);   // RNE
    return (u16)(r >> 16);
}
__device__ __forceinline__ float ldin(const void* p, long i, int bf) {
    return bf ? b2f(((const u16*)p)[i]) : ((const float*)p)[i];
}
__device__ __forceinline__ float sigm(float x) { return 1.0f / (1.0f + __expf(-x)); }
__device__ __forceinline__ float tanh_f(float x) { return 2.0f / (1.0f + __expf(-2.0f * x)) - 1.0f; }

// ---- detect whether float inputs are bf16 or f32, from `trans` (400 uniform(-0.1,0.1)) ----
__global__ void sniff_k(const unsigned char* __restrict__ traw, int* __restrict__ flag) {
    int lane = threadIdx.x;
    int votes = 0;
    for (int w = lane; w < 200; w += 64) {
        unsigned char b1 = traw[w * 4 + 1];
        unsigned char e = b1 & 0x7F;
        if (e >= 0x20 && e <= 0x3E) votes++;
    }
    #pragma unroll
    for (int off = 32; off; off >>= 1) votes += __shfl_xor(votes, off);
    if (lane == 0) *flag = (votes > 120) ? 1 : 0;
}

// ---- convert all weights into canonical ws copies (bf16 matrices, f32 vectors) ----
__global__ __launch_bounds__(256) void prep_k(
    const void* wih0, const void* whh0, const void* b0,
    const void* wih1, const void* whh1, const void* b1,
    const void* wout, const void* bout, const void* trans,
    const void* start, const void* end, unsigned char* ws)
{
    const int bf = *(const int*)(ws + OFF_FLAG);
    long tid = (long)blockIdx.x * 256 + threadIdx.x;
    u16* wih0b = (u16*)(ws + OFF_WIH0);
    u16* whh0b = (u16*)(ws + OFF_WHH0);
    u16* wih1b = (u16*)(ws + OFF_WIH1);
    u16* whh1b = (u16*)(ws + OFF_WHH1);
    u16* woutb = (u16*)(ws + OFF_WOUT);
    float* b0f   = (float*)(ws + OFF_B0);
    float* b1f   = (float*)(ws + OFF_B1);
    float* boutf = (float*)(ws + OFF_BOUT);
    float* trf   = (float*)(ws + OFF_TRANS);
    float* stf   = (float*)(ws + OFF_START);
    float* enf   = (float*)(ws + OFF_END);

    if (tid < 131072) { wih0b[tid] = f2b(ldin(wih0, tid, bf)); return; } tid -= 131072;
    if (tid < 131072) { whh0b[tid] = f2b(ldin(whh0, tid, bf)); return; } tid -= 131072;
    if (tid < 1024)   { b0f[tid]   = ldin(b0, tid, bf);        return; } tid -= 1024;
    if (tid < 262144) { wih1b[tid] = f2b(ldin(wih1, tid, bf)); return; } tid -= 262144;
    if (tid < 131072) { whh1b[tid] = f2b(ldin(whh1, tid, bf)); return; } tid -= 131072;
    if (tid < 1024)   { b1f[tid]   = ldin(b1, tid, bf);        return; } tid -= 1024;
    if (tid < 5120)   { woutb[tid] = f2b(ldin(wout, tid, bf)); return; } tid -= 5120;
    if (tid < 20)     { boutf[tid] = ldin(bout, tid, bf);      return; } tid -= 20;
    if (tid < 400)    { trf[tid]   = ldin(trans, tid, bf);     return; } tid -= 400;
    if (tid < 20)     { stf[tid]   = ldin(start, tid, bf);     return; } tid -= 20;
    if (tid < 20)     { enf[tid]   = ldin(end, tid, bf);       return; }
}

// ---- embedding gather -> x0 bf16 [m = t*CB+b][128] ----
__global__ __launch_bounds__(256) void gather_k(const void* __restrict__ embed,
                                                const int* __restrict__ sent,
                                                unsigned char* __restrict__ ws)
{
    const int bf = *(const int*)(ws + OFF_FLAG);
    u16* x0 = (u16*)(ws + OFF_X0);
    int tid = blockIdx.x * 256 + threadIdx.x;      // 1,048,576 threads
    int m = tid >> 4, ch = tid & 15;               // 16 chunks of 8 elems per row
    int t = m >> 7, b = m & 127;
    int s = sent[b * CT + t];
    long src = (long)s * CE + ch * 8;
    u16x8 o;
    if (bf) {
        o = *(const u16x8*)((const u16*)embed + src);
    } else {
        const float* ef = (const float*)embed + src;
        f32x4 lo = *(const f32x4*)ef;
        f32x4 hi = *(const f32x4*)(ef + 4);
        o[0]=f2b(lo[0]); o[1]=f2b(lo[1]); o[2]=f2b(lo[2]); o[3]=f2b(lo[3]);
        o[4]=f2b(hi[0]); o[5]=f2b(hi[1]); o[6]=f2b(hi[2]); o[7]=f2b(hi[3]);
    }
    *(u16x8*)(x0 + (long)m * CE + ch * 8) = o;
}

// ---- bf16 MFMA GEMM: C[M,1024] = A[M,KD] @ B[1024,KD]^T, C stored bf16 ----
template<int KD>
__global__ __launch_bounds__(256) void gemm_k(const u16* __restrict__ A,
                                              const u16* __restrict__ Bw,
                                              u16* __restrict__ C)
{
    const int wave = threadIdx.x >> 6, lane = threadIdx.x & 63;
    const int lr = lane & 15, kg = (lane >> 4) * 8;
    const long m0 = (long)blockIdx.x * 16;
    const int n0 = wave * 256;
    const u16* Ap = A + (m0 + lr) * KD + kg;
    const u16* Bp = Bw + (long)(n0 + lr) * KD + kg;
    f32x4 acc[16];
    #pragma unroll
    for (int i = 0; i < 16; ++i) acc[i] = (f32x4){0.f, 0.f, 0.f, 0.f};
    #pragma unroll
    for (int kk = 0; kk < KD; kk += 32) {
        bf16x8 av = *(const bf16x8*)(Ap + kk);
        #pragma unroll
        for (int nt = 0; nt < 16; ++nt) {
            bf16x8 bv = *(const bf16x8*)(Bp + (long)nt * 16 * KD + kk);
            acc[nt] = __builtin_amdgcn_mfma_f32_16x16x32_bf16(av, bv, acc[nt], 0, 0, 0);
        }
    }
    const int rr0 = (lane >> 4) * 4;
    #pragma unroll
    for (int nt = 0; nt < 16; ++nt) {
        int col = n0 + nt * 16 + lr;
        #pragma unroll
        for (int r = 0; r < 4; ++r) {
            long row = m0 + rr0 + r;
            C[row * 1024 + col] = f2b(acc[nt][r]);
        }
    }
}

// ---- LSTM scan: one block per (batch b, direction d); 512 threads = one per gate row ----
// w[128] MUST stay register-resident: dot loop fully unrolled (rule #20).
__global__ __launch_bounds__(512, 2) void scan_k(const u16* __restrict__ Z,
                                                 const u16* __restrict__ Whh,
                                                 const float* __restrict__ bias,
                                                 u16* __restrict__ hout)
{
    const int b = blockIdx.x & 127, d = blockIdx.x >> 7;
    const int g = threadIdx.x;                 // gate row 0..511 (i,f,g,o blocks of 128)
    const u16* wrow = Whh + (long)(d * 512 + g) * 128;
    float w[128];
    #pragma unroll
    for (int k8 = 0; k8 < 16; ++k8) {
        u16x8 u = *(const u16x8*)(wrow + k8 * 8);
        #pragma unroll
        for (int j = 0; j < 8; ++j) w[k8 * 8 + j] = b2f(u[j]);
    }
    const float bg = bias[d * 512 + g];
    __shared__ __align__(16) float hbuf[128];
    __shared__ float zbuf[512];
    float c = 0.f;
    if (g < 128) hbuf[g] = 0.f;
    __syncthreads();

    const long zbase = (long)b * 1024 + (long)d * 512 + g;
    u16 zraw = Z[(long)(d ? CT - 1 : 0) * (CB * 1024) + zbase];
    u16* hrow = hout + (long)b * 256 + d * 128 + g;   // valid only for g<128
    for (int s = 0; s < CT; ++s) {
        const int t = d ? (CT - 1 - s) : s;
        const float zx = b2f(zraw);
        if (s + 1 < CT) {                       // prefetch next step's xW term
            const int tn = d ? (CT - 2 - s) : (s + 1);
            zraw = Z[(long)tn * (CB * 1024) + zbase];
        }
        float a0 = 0.f, a1 = 0.f, a2 = 0.f, a3 = 0.f;
        #pragma unroll
        for (int k = 0; k < 128; k += 4) {
            f32x4 h4 = *(const f32x4*)(hbuf + k);
            a0 = fmaf(w[k + 0], h4[0], a0);
            a1 = fmaf(w[k + 1], h4[1], a1);
            a2 = fmaf(w[k + 2], h4[2], a2);
            a3 = fmaf(w[k + 3], h4[3], a3);
        }
        const float z = (a0 + a1) + (a2 + a3) + zx + bg;
        const float act = (g >= 256 && g < 384) ? tanh_f(z) : sigm(z);
        zbuf[g] = act;
        __syncthreads();
        if (g < 128) {
            const float iv = zbuf[g], fv = zbuf[g + 128], gv = zbuf[g + 256], ov = zbuf[g + 384];
            c = fmaf(fv, c, iv * gv);
            const float h = ov * tanh_f(c);
            hbuf[g] = h;
            hrow[(long)t * CB * 256] = f2b(h);
        }
        __syncthreads();
    }
}

// ---- emissions: em[m][20] = h1[m] @ Wout^T + bout (f32) ----
__global__ __launch_bounds__(256) void emis_k(const u16* __restrict__ h1,
                                              const u16* __restrict__ woutb,
                                              const float* __restrict__ boutf,
                                              float* __restrict__ em)
{
    __shared__ __align__(16) float wsm[CK * 256];
    for (int i = threadIdx.x; i < CK * 256; i += 256) wsm[i] = b2f(woutb[i]);
    __syncthreads();
    const long m = (long)blockIdx.x * 256 + threadIdx.x;
    const u16* hrow = h1 + m * 256;
    float acc[CK];
    #pragma unroll
    for (int n = 0; n < CK; ++n) acc[n] = boutf[n];
    for (int k8 = 0; k8 < 32; ++k8) {
        u16x8 u = *(const u16x8*)(hrow + k8 * 8);
        float hv[8];
        #pragma unroll
        for (int j = 0; j < 8; ++j) hv[j] = b2f(u[j]);
        #pragma unroll
        for (int n = 0; n < CK; ++n) {
            const f32x4 w0 = *(const f32x4*)&wsm[n * 256 + k8 * 8];
            const f32x4 w1 = *(const f32x4*)&wsm[n * 256 + k8 * 8 + 4];
            acc[n] = fmaf(hv[0], w0[0], acc[n]); acc[n] = fmaf(hv[1], w0[1], acc[n]);
            acc[n] = fmaf(hv[2], w0[2], acc[n]); acc[n] = fmaf(hv[3], w0[3], acc[n]);
            acc[n] = fmaf(hv[4], w1[0], acc[n]); acc[n] = fmaf(hv[5], w1[1], acc[n]);
            acc[n] = fmaf(hv[6], w1[2], acc[n]); acc[n] = fmaf(hv[7], w1[3], acc[n]);
        }
    }
    float* emrow = em + m * CK;
    #pragma unroll
    for (int n = 0; n < CK; ++n) emrow[n] = acc[n];
}

// ---- CRF ----
// blocks 0..63: alpha-scan, TWO batches per wave (lanes 0-19 -> b=2*blk, lanes 32-51 -> 2*blk+1)
// blocks 64..191: numerator for b = blockIdx-64
__global__ void crf_k(const float* __restrict__ em, const int* __restrict__ tags,
                      const float* __restrict__ trf, const float* __restrict__ stf,
                      const float* __restrict__ enf, float* __restrict__ partial)
{
    const int lane = threadIdx.x;      // 64
    if (blockIdx.x < 64) {
        const int j = lane & 31, half = lane >> 5;
        const int b = blockIdx.x * 2 + half;
        const bool act = j < CK;
        float tcol[CK];
        #pragma unroll
        for (int i = 0; i < CK; ++i) tcol[i] = act ? trf[i * CK + j] : 0.f;
        float alpha = act ? (stf[j] + em[(long)b * CK + j]) : -1e30f;
        for (int t = 1; t < CT; ++t) {
            float v[CK];
            #pragma unroll
            for (int i = 0; i < CK; ++i)
                v[i] = __shfl(alpha, i, 32) + tcol[i];      // width-32: per-half broadcast
            // tree max over 20
            float m1[10], m2[5];
            #pragma unroll
            for (int i = 0; i < 10; ++i) m1[i] = fmaxf(v[2 * i], v[2 * i + 1]);
            #pragma unroll
            for (int i = 0; i < 5; ++i) m2[i] = fmaxf(m1[2 * i], m1[2 * i + 1]);
            const float mx = fmaxf(fmaxf(fmaxf(m2[0], m2[1]), fmaxf(m2[2], m2[3])), m2[4]);
            float e[CK];
            #pragma unroll
            for (int i = 0; i < CK; ++i) e[i] = __expf(v[i] - mx);
            float s1[10], s2[5];
            #pragma unroll
            for (int i = 0; i < 10; ++i) s1[i] = e[2 * i] + e[2 * i + 1];
            #pragma unroll
            for (int i = 0; i < 5; ++i) s2[i] = s1[2 * i] + s1[2 * i + 1];
            const float s = (s2[0] + s2[1]) + (s2[2] + s2[3]) + s2[4];
            const float emv = act ? em[((long)t * CB + b) * CK + j] : 0.f;
            const float na = mx + __logf(s) + emv;
            alpha = act ? na : -1e30f;
        }
        float vv = act ? (alpha + enf[j]) : -1e30f;
        float mx = vv;
        #pragma unroll
        for (int off = 16; off; off >>= 1) mx = fmaxf(mx, __shfl_xor(mx, off, 32));
        float ex = act ? __expf(vv - mx) : 0.f;
        #pragma unroll
        for (int off = 16; off; off >>= 1) ex += __shfl_xor(ex, off, 32);
        if (j == 0) partial[b] = mx + __logf(ex);
    } else {
        const int b = blockIdx.x - 64;
        float sc = 0.f;
        for (int t = lane; t < CT; t += 64) {
            const int tg = tags[b * CT + t];
            sc += em[((long)t * CB + b) * CK + tg];
            if (t >= 1) sc += trf[tags[b * CT + t - 1] * CK + tg];
        }
        #pragma unroll
        for (int off = 32; off; off >>= 1) sc += __shfl_xor(sc, off);
        if (lane == 0)
            partial[128 + b] = sc + stf[tags[b * CT]] + enf[tags[b * CT + CT - 1]];
    }
}

__global__ void fin_k(const float* __restrict__ partial, void* __restrict__ out,
                      const unsigned char* __restrict__ ws)
{
    const int bf = *(const int*)(ws + OFF_FLAG);
    const int lane = threadIdx.x;  // 64
    float v = (partial[lane] - partial[128 + lane]) + (partial[lane + 64] - partial[192 + lane]);
    #pragma unroll
    for (int off = 32; off; off >>= 1) v += __shfl_xor(v, off);
    if (lane == 0) {
        const float mean = v / 128.f;
        if (bf) ((u16*)out)[0] = f2b(mean);
        else    ((float*)out)[0] = mean;
    }
}

extern "C" void kernel_launch(void* const* d_in, const int* in_sizes, int n_in,
                              void* d_out, int out_size, void* d_ws, size_t ws_size,
                              hipStream_t stream) {
    (void)in_sizes; (void)n_in; (void)out_size;
    if (ws_size < WS_NEED) return;
    unsigned char* ws = (unsigned char*)d_ws;

    const void* sent  = d_in[0];
    const void* tags  = d_in[1];
    const void* embed = d_in[3];

    u16* x0  = (u16*)(ws + OFF_X0);
    u16* h0  = (u16*)(ws + OFF_H0);
    u16* h1  = (u16*)(ws + OFF_H1);
    u16* Zb  = (u16*)(ws + OFF_Z);
    float* em = (float*)(ws + OFF_EM);
    float* part = (float*)(ws + OFF_PART);

    sniff_k<<<1, 64, 0, stream>>>((const unsigned char*)d_in[12], (int*)(ws + OFF_FLAG));
    prep_k<<<2590, 256, 0, stream>>>(d_in[4], d_in[5], d_in[6], d_in[7], d_in[8],
                                     d_in[9], d_in[10], d_in[11], d_in[12], d_in[13],
                                     d_in[14], ws);
    gather_k<<<4096, 256, 0, stream>>>(embed, (const int*)sent, ws);
    // layer 0
    gemm_k<128><<<4096, 256, 0, stream>>>(x0, (const u16*)(ws + OFF_WIH0), Zb);
    scan_k<<<256, 512, 0, stream>>>(Zb, (const u16*)(ws + OFF_WHH0),
                                    (const float*)(ws + OFF_B0), h0);
    // layer 1
    gemm_k<256><<<4096, 256, 0, stream>>>(h0, (const u16*)(ws + OFF_WIH1), Zb);
    scan_k<<<256, 512, 0, stream>>>(Zb, (const u16*)(ws + OFF_WHH1),
                                    (const float*)(ws + OFF_B1), h1);
    // emissions + CRF
    emis_k<<<256, 256, 0, stream>>>(h1, (const u16*)(ws + OFF_WOUT),
                                    (const float*)(ws + OFF_BOUT), em);
    crf_k<<<192, 64, 0, stream>>>(em, (const int*)tags,
                                  (const float*)(ws + OFF_TRANS),
                                  (const float*)(ws + OFF_START),
                                  (const float*)(ws + OFF_END), part);
    fin_k<<<1, 64, 0, stream>>>(part, d_out, ws);
}

// Round 3
// 1539.816 us; speedup vs baseline: 1.0819x; 1.0819x over previous
//
#include <hip/hip_runtime.h>
#include <hip/hip_bf16.h>
#include <cstddef>

typedef unsigned short u16;
typedef short bf16x8 __attribute__((ext_vector_type(8)));
typedef unsigned short u16x8 __attribute__((ext_vector_type(8)));
typedef float f32x4 __attribute__((ext_vector_type(4)));

constexpr int CB = 128;    // batch
constexpr int CT = 512;    // time
constexpr int CE = 128;    // embed dim
constexpr int CK = 20;     // tags

// ---- workspace layout (bytes) ----
constexpr size_t OFF_FLAG  = 0;                       // int dtype flag (1=bf16 inputs)
constexpr size_t OFF_WIH0  = 256;                     // bf16 [1024][128]
constexpr size_t OFF_WHH0  = OFF_WIH0 + 262144;       // bf16 [1024][128]
constexpr size_t OFF_WIH1  = OFF_WHH0 + 262144;       // bf16 [1024][256]
constexpr size_t OFF_WHH1  = OFF_WIH1 + 524288;       // bf16 [1024][128]
constexpr size_t OFF_WOUT  = OFF_WHH1 + 262144;       // bf16 [20][256]
constexpr size_t OFF_B0    = OFF_WOUT + 10240;        // f32 [1024]
constexpr size_t OFF_B1    = OFF_B0 + 4096;           // f32 [1024]
constexpr size_t OFF_BOUT  = OFF_B1 + 4096;           // f32 [20]
constexpr size_t OFF_TRANS = OFF_BOUT + 256;          // f32 [400]
constexpr size_t OFF_START = OFF_TRANS + 1792;        // f32 [20]
constexpr size_t OFF_END   = OFF_START + 256;         // f32 [20]
constexpr size_t OFF_PART  = OFF_END + 256;           // f32 [256]: logZ[128], score[128]
constexpr size_t OFF_X0    = 2097152;                 // bf16 [65536][128]
constexpr size_t OFF_H0    = OFF_X0 + 16777216;       // bf16 [65536][256]
constexpr size_t OFF_H1    = OFF_H0 + 33554432;       // bf16 [65536][256]
constexpr size_t OFF_EM    = OFF_H1 + 33554432;       // f32  [65536][20]
constexpr size_t OFF_Z     = OFF_EM + 5242880;        // bf16 [65536][1024] (reused L0/L1)
constexpr size_t WS_NEED   = OFF_Z + 134217728;       // ~225.4 MB

__device__ __forceinline__ float b2f(u16 u) {
    union { unsigned int i; float f; } v; v.i = ((unsigned int)u) << 16; return v.f;
}
__device__ __forceinline__ u16 f2b(float f) {
    union { float f; unsigned int i; } v; v.f = f;
    unsigned int r = v.i + 0x7FFFu + ((v.i >> 16) & 1u);   // RNE
    return (u16)(r >> 16);
}
__device__ __forceinline__ float ldin(const void* p, long i, int bf) {
    return bf ? b2f(((const u16*)p)[i]) : ((const float*)p)[i];
}
__device__ __forceinline__ float sigm(float x) { return 1.0f / (1.0f + __expf(-x)); }
__device__ __forceinline__ float tanh_f(float x) { return 2.0f / (1.0f + __expf(-2.0f * x)) - 1.0f; }

// ---- detect whether float inputs are bf16 or f32, from `trans` (400 uniform(-0.1,0.1)) ----
__global__ void sniff_k(const unsigned char* __restrict__ traw, int* __restrict__ flag) {
    int lane = threadIdx.x;
    int votes = 0;
    for (int w = lane; w < 200; w += 64) {
        unsigned char b1 = traw[w * 4 + 1];
        unsigned char e = b1 & 0x7F;
        if (e >= 0x20 && e <= 0x3E) votes++;
    }
    #pragma unroll
    for (int off = 32; off; off >>= 1) votes += __shfl_xor(votes, off);
    if (lane == 0) *flag = (votes > 120) ? 1 : 0;
}

// ---- convert all weights into canonical ws copies (bf16 matrices, f32 vectors) ----
__global__ __launch_bounds__(256) void prep_k(
    const void* wih0, const void* whh0, const void* b0,
    const void* wih1, const void* whh1, const void* b1,
    const void* wout, const void* bout, const void* trans,
    const void* start, const void* end, unsigned char* ws)
{
    const int bf = *(const int*)(ws + OFF_FLAG);
    long tid = (long)blockIdx.x * 256 + threadIdx.x;
    u16* wih0b = (u16*)(ws + OFF_WIH0);
    u16* whh0b = (u16*)(ws + OFF_WHH0);
    u16* wih1b = (u16*)(ws + OFF_WIH1);
    u16* whh1b = (u16*)(ws + OFF_WHH1);
    u16* woutb = (u16*)(ws + OFF_WOUT);
    float* b0f   = (float*)(ws + OFF_B0);
    float* b1f   = (float*)(ws + OFF_B1);
    float* boutf = (float*)(ws + OFF_BOUT);
    float* trf   = (float*)(ws + OFF_TRANS);
    float* stf   = (float*)(ws + OFF_START);
    float* enf   = (float*)(ws + OFF_END);

    if (tid < 131072) { wih0b[tid] = f2b(ldin(wih0, tid, bf)); return; } tid -= 131072;
    if (tid < 131072) { whh0b[tid] = f2b(ldin(whh0, tid, bf)); return; } tid -= 131072;
    if (tid < 1024)   { b0f[tid]   = ldin(b0, tid, bf);        return; } tid -= 1024;
    if (tid < 262144) { wih1b[tid] = f2b(ldin(wih1, tid, bf)); return; } tid -= 262144;
    if (tid < 131072) { whh1b[tid] = f2b(ldin(whh1, tid, bf)); return; } tid -= 131072;
    if (tid < 1024)   { b1f[tid]   = ldin(b1, tid, bf);        return; } tid -= 1024;
    if (tid < 5120)   { woutb[tid] = f2b(ldin(wout, tid, bf)); return; } tid -= 5120;
    if (tid < 20)     { boutf[tid] = ldin(bout, tid, bf);      return; } tid -= 20;
    if (tid < 400)    { trf[tid]   = ldin(trans, tid, bf);     return; } tid -= 400;
    if (tid < 20)     { stf[tid]   = ldin(start, tid, bf);     return; } tid -= 20;
    if (tid < 20)     { enf[tid]   = ldin(end, tid, bf);       return; }
}

// ---- embedding gather -> x0 bf16 [m = t*CB+b][128] ----
__global__ __launch_bounds__(256) void gather_k(const void* __restrict__ embed,
                                                const int* __restrict__ sent,
                                                unsigned char* __restrict__ ws)
{
    const int bf = *(const int*)(ws + OFF_FLAG);
    u16* x0 = (u16*)(ws + OFF_X0);
    int tid = blockIdx.x * 256 + threadIdx.x;      // 1,048,576 threads
    int m = tid >> 4, ch = tid & 15;               // 16 chunks of 8 elems per row
    int t = m >> 7, b = m & 127;
    int s = sent[b * CT + t];
    long src = (long)s * CE + ch * 8;
    u16x8 o;
    if (bf) {
        o = *(const u16x8*)((const u16*)embed + src);
    } else {
        const float* ef = (const float*)embed + src;
        f32x4 lo = *(const f32x4*)ef;
        f32x4 hi = *(const f32x4*)(ef + 4);
        o[0]=f2b(lo[0]); o[1]=f2b(lo[1]); o[2]=f2b(lo[2]); o[3]=f2b(lo[3]);
        o[4]=f2b(hi[0]); o[5]=f2b(hi[1]); o[6]=f2b(hi[2]); o[7]=f2b(hi[3]);
    }
    *(u16x8*)(x0 + (long)m * CE + ch * 8) = o;
}

// ---- bf16 MFMA GEMM: C[M,1024] = A[M,KD] @ B[1024,KD]^T, C stored bf16 ----
template<int KD>
__global__ __launch_bounds__(256) void gemm_k(const u16* __restrict__ A,
                                              const u16* __restrict__ Bw,
                                              u16* __restrict__ C)
{
    const int wave = threadIdx.x >> 6, lane = threadIdx.x & 63;
    const int lr = lane & 15, kg = (lane >> 4) * 8;
    const long m0 = (long)blockIdx.x * 16;
    const int n0 = wave * 256;
    const u16* Ap = A + (m0 + lr) * KD + kg;
    const u16* Bp = Bw + (long)(n0 + lr) * KD + kg;
    f32x4 acc[16];
    #pragma unroll
    for (int i = 0; i < 16; ++i) acc[i] = (f32x4){0.f, 0.f, 0.f, 0.f};
    #pragma unroll
    for (int kk = 0; kk < KD; kk += 32) {
        bf16x8 av = *(const bf16x8*)(Ap + kk);
        #pragma unroll
        for (int nt = 0; nt < 16; ++nt) {
            bf16x8 bv = *(const bf16x8*)(Bp + (long)nt * 16 * KD + kk);
            acc[nt] = __builtin_amdgcn_mfma_f32_16x16x32_bf16(av, bv, acc[nt], 0, 0, 0);
        }
    }
    const int rr0 = (lane >> 4) * 4;
    #pragma unroll
    for (int nt = 0; nt < 16; ++nt) {
        int col = n0 + nt * 16 + lr;
        #pragma unroll
        for (int r = 0; r < 4; ++r) {
            long row = m0 + rr0 + r;
            C[row * 1024 + col] = f2b(acc[nt][r]);
        }
    }
}

// ---- LSTM scan, MFMA edition: one block per (batch b, direction d) ----
// 512 threads = 8 waves; wave w owns gates [w*64, w*64+64).
// Whh lives in B-fragments (64 VGPR, loaded once). h is broadcast to all 16
// A-rows (every C row computes the same h.Whh^T -> read row 0's value from any
// acc element). h history staged 8 steps in LDS, flushed to hout every 8 steps
// so per-step barriers don't drain a global store.
__global__ __launch_bounds__(512, 2) void scan_k(const u16* __restrict__ Z,
                                                 const u16* __restrict__ Whh,
                                                 const float* __restrict__ bias,
                                                 u16* __restrict__ hout)
{
    const int b = blockIdx.x & 127, d = blockIdx.x >> 7;
    const int tid = threadIdx.x;
    const int wave = tid >> 6, lane = tid & 63;
    const int lr = lane & 15, kg = (lane >> 4) * 8;
    const int n0 = wave * 64;

    // B-fragments: bfrag[nt][kt] = Whh[d*512 + n0 + nt*16 + lr][kt*32 + kg .. +7]
    bf16x8 bfrag[4][4];
    const u16* wbase = Whh + (long)(d * 512 + n0 + lr) * 128 + kg;
    #pragma unroll
    for (int nt = 0; nt < 4; ++nt)
        #pragma unroll
        for (int kt = 0; kt < 4; ++kt)
            bfrag[nt][kt] = *(const bf16x8*)(wbase + (long)nt * 16 * 128 + kt * 32);

    float bg[4];
    #pragma unroll
    for (int nt = 0; nt < 4; ++nt) bg[nt] = bias[d * 512 + n0 + nt * 16 + lr];

    __shared__ __align__(16) u16 hbuf[128];     // current h, bf16
    __shared__ float zact[512];                 // activated gates
    __shared__ __align__(16) u16 hist8[8 * 128];// 8-step h history

    float c = 0.f;                               // cell state for tid<128
    if (tid < 128) hbuf[tid] = 0;
    __syncthreads();

    const int dt = d ? -1 : 1;
    int t = d ? (CT - 1) : 0;
    const u16* zp = Z + (long)b * 1024 + d * 512 + n0 + lr;  // + t*131072 + nt*16
    u16 zr[4];
    #pragma unroll
    for (int nt = 0; nt < 4; ++nt) zr[nt] = zp[(long)t * (CB * 1024) + nt * 16];

    for (int s = 0; s < CT; ++s) {
        float zx[4];
        #pragma unroll
        for (int nt = 0; nt < 4; ++nt) zx[nt] = b2f(zr[nt]);
        const int tn = t + dt;
        if (s + 1 < CT) {
            #pragma unroll
            for (int nt = 0; nt < 4; ++nt) zr[nt] = zp[(long)tn * (CB * 1024) + nt * 16];
        }

        // A-fragments: same h chunk for all lanes in a 16-lane group (broadcast)
        bf16x8 av[4];
        #pragma unroll
        for (int kt = 0; kt < 4; ++kt)
            av[kt] = *(const bf16x8*)(hbuf + kt * 32 + kg);

        f32x4 acc0[4], acc1[4];   // two independent k-chains
        #pragma unroll
        for (int nt = 0; nt < 4; ++nt) {
            acc0[nt] = (f32x4){0.f, 0.f, 0.f, 0.f};
            acc1[nt] = (f32x4){0.f, 0.f, 0.f, 0.f};
        }
        #pragma unroll
        for (int nt = 0; nt < 4; ++nt) {
            acc0[nt] = __builtin_amdgcn_mfma_f32_16x16x32_bf16(av[0], bfrag[nt][0], acc0[nt], 0, 0, 0);
            acc1[nt] = __builtin_amdgcn_mfma_f32_16x16x32_bf16(av[1], bfrag[nt][1], acc1[nt], 0, 0, 0);
            acc0[nt] = __builtin_amdgcn_mfma_f32_16x16x32_bf16(av[2], bfrag[nt][2], acc0[nt], 0, 0, 0);
            acc1[nt] = __builtin_amdgcn_mfma_f32_16x16x32_bf16(av[3], bfrag[nt][3], acc1[nt], 0, 0, 0);
        }

        // z and activation (wave-uniform gate type: wave>>1 -> 0:i 1:f 2:g 3:o)
        float av4[4];
        if ((wave >> 1) == 2) {
            #pragma unroll
            for (int nt = 0; nt < 4; ++nt)
                av4[nt] = tanh_f(acc0[nt][0] + acc1[nt][0] + zx[nt] + bg[nt]);
        } else {
            #pragma unroll
            for (int nt = 0; nt < 4; ++nt)
                av4[nt] = sigm(acc0[nt][0] + acc1[nt][0] + zx[nt] + bg[nt]);
        }
        if (lane < 16) {
            #pragma unroll
            for (int nt = 0; nt < 4; ++nt) zact[n0 + nt * 16 + lr] = av4[nt];
        }
        __syncthreads();

        if (tid < 128) {
            const float iv = zact[tid], fv = zact[tid + 128];
            const float gv = zact[tid + 256], ov = zact[tid + 384];
            c = fmaf(fv, c, iv * gv);
            const float h = ov * tanh_f(c);
            const u16 hb = f2b(h);
            hbuf[tid] = hb;
            hist8[(s & 7) * 128 + tid] = hb;
        }
        __syncthreads();

        if ((s & 7) == 7 && tid < 128) {        // flush 8 steps of h to global
            const int u = tid >> 4;
            const int tu = t - dt * (7 - u);
            *(u16x8*)(hout + ((long)tu * CB + b) * 256 + d * 128 + (tid & 15) * 8) =
                *(const u16x8*)(hist8 + u * 128 + (tid & 15) * 8);
        }
        t = tn;
    }
}

// ---- emissions: em[m][20] = h1[m] @ Wout^T + bout (f32) ----
__global__ __launch_bounds__(256) void emis_k(const u16* __restrict__ h1,
                                              const u16* __restrict__ woutb,
                                              const float* __restrict__ boutf,
                                              float* __restrict__ em)
{
    __shared__ __align__(16) float wsm[CK * 256];
    for (int i = threadIdx.x; i < CK * 256; i += 256) wsm[i] = b2f(woutb[i]);
    __syncthreads();
    const long m = (long)blockIdx.x * 256 + threadIdx.x;
    const u16* hrow = h1 + m * 256;
    float acc[CK];
    #pragma unroll
    for (int n = 0; n < CK; ++n) acc[n] = boutf[n];
    for (int k8 = 0; k8 < 32; ++k8) {
        u16x8 u = *(const u16x8*)(hrow + k8 * 8);
        float hv[8];
        #pragma unroll
        for (int j = 0; j < 8; ++j) hv[j] = b2f(u[j]);
        #pragma unroll
        for (int n = 0; n < CK; ++n) {
            const f32x4 w0 = *(const f32x4*)&wsm[n * 256 + k8 * 8];
            const f32x4 w1 = *(const f32x4*)&wsm[n * 256 + k8 * 8 + 4];
            acc[n] = fmaf(hv[0], w0[0], acc[n]); acc[n] = fmaf(hv[1], w0[1], acc[n]);
            acc[n] = fmaf(hv[2], w0[2], acc[n]); acc[n] = fmaf(hv[3], w0[3], acc[n]);
            acc[n] = fmaf(hv[4], w1[0], acc[n]); acc[n] = fmaf(hv[5], w1[1], acc[n]);
            acc[n] = fmaf(hv[6], w1[2], acc[n]); acc[n] = fmaf(hv[7], w1[3], acc[n]);
        }
    }
    float* emrow = em + m * CK;
    #pragma unroll
    for (int n = 0; n < CK; ++n) emrow[n] = acc[n];
}

// ---- CRF ----
__global__ void crf_k(const float* __restrict__ em, const int* __restrict__ tags,
                      const float* __restrict__ trf, const float* __restrict__ stf,
                      const float* __restrict__ enf, float* __restrict__ partial)
{
    const int lane = threadIdx.x;      // 64
    if (blockIdx.x < 64) {
        const int j = lane & 31, half = lane >> 5;
        const int b = blockIdx.x * 2 + half;
        const bool act = j < CK;
        float tcol[CK];
        #pragma unroll
        for (int i = 0; i < CK; ++i) tcol[i] = act ? trf[i * CK + j] : 0.f;
        float alpha = act ? (stf[j] + em[(long)b * CK + j]) : -1e30f;
        for (int t = 1; t < CT; ++t) {
            float v[CK];
            #pragma unroll
            for (int i = 0; i < CK; ++i)
                v[i] = __shfl(alpha, i, 32) + tcol[i];
            float m1[10], m2[5];
            #pragma unroll
            for (int i = 0; i < 10; ++i) m1[i] = fmaxf(v[2 * i], v[2 * i + 1]);
            #pragma unroll
            for (int i = 0; i < 5; ++i) m2[i] = fmaxf(m1[2 * i], m1[2 * i + 1]);
            const float mx = fmaxf(fmaxf(fmaxf(m2[0], m2[1]), fmaxf(m2[2], m2[3])), m2[4]);
            float e[CK];
            #pragma unroll
            for (int i = 0; i < CK; ++i) e[i] = __expf(v[i] - mx);
            float s1[10], s2[5];
            #pragma unroll
            for (int i = 0; i < 10; ++i) s1[i] = e[2 * i] + e[2 * i + 1];
            #pragma unroll
            for (int i = 0; i < 5; ++i) s2[i] = s1[2 * i] + s1[2 * i + 1];
            const float s = (s2[0] + s2[1]) + (s2[2] + s2[3]) + s2[4];
            const float emv = act ? em[((long)t * CB + b) * CK + j] : 0.f;
            const float na = mx + __logf(s) + emv;
            alpha = act ? na : -1e30f;
        }
        float vv = act ? (alpha + enf[j]) : -1e30f;
        float mx = vv;
        #pragma unroll
        for (int off = 16; off; off >>= 1) mx = fmaxf(mx, __shfl_xor(mx, off, 32));
        float ex = act ? __expf(vv - mx) : 0.f;
        #pragma unroll
        for (int off = 16; off; off >>= 1) ex += __shfl_xor(ex, off, 32);
        if (j == 0) partial[b] = mx + __logf(ex);
    } else {
        const int b = blockIdx.x - 64;
        float sc = 0.f;
        for (int t = lane; t < CT; t += 64) {
            const int tg = tags[b * CT + t];
            sc += em[((long)t * CB + b) * CK + tg];
            if (t >= 1) sc += trf[tags[b * CT + t - 1] * CK + tg];
        }
        #pragma unroll
        for (int off = 32; off; off >>= 1) sc += __shfl_xor(sc, off);
        if (lane == 0)
            partial[128 + b] = sc + stf[tags[b * CT]] + enf[tags[b * CT + CT - 1]];
    }
}

__global__ void fin_k(const float* __restrict__ partial, void* __restrict__ out,
                      const unsigned char* __restrict__ ws)
{
    const int bf = *(const int*)(ws + OFF_FLAG);
    const int lane = threadIdx.x;  // 64
    float v = (partial[lane] - partial[128 + lane]) + (partial[lane + 64] - partial[192 + lane]);
    #pragma unroll
    for (int off = 32; off; off >>= 1) v += __shfl_xor(v, off);
    if (lane == 0) {
        const float mean = v / 128.f;
        if (bf) ((u16*)out)[0] = f2b(mean);
        else    ((float*)out)[0] = mean;
    }
}

extern "C" void kernel_launch(void* const* d_in, const int* in_sizes, int n_in,
                              void* d_out, int out_size, void* d_ws, size_t ws_size,
                              hipStream_t stream) {
    (void)in_sizes; (void)n_in; (void)out_size;
    if (ws_size < WS_NEED) return;
    unsigned char* ws = (unsigned char*)d_ws;

    const void* sent  = d_in[0];
    const void* tags  = d_in[1];
    const void* embed = d_in[3];

    u16* x0  = (u16*)(ws + OFF_X0);
    u16* h0  = (u16*)(ws + OFF_H0);
    u16* h1  = (u16*)(ws + OFF_H1);
    u16* Zb  = (u16*)(ws + OFF_Z);
    float* em = (float*)(ws + OFF_EM);
    float* part = (float*)(ws + OFF_PART);

    sniff_k<<<1, 64, 0, stream>>>((const unsigned char*)d_in[12], (int*)(ws + OFF_FLAG));
    prep_k<<<2590, 256, 0, stream>>>(d_in[4], d_in[5], d_in[6], d_in[7], d_in[8],
                                     d_in[9], d_in[10], d_in[11], d_in[12], d_in[13],
                                     d_in[14], ws);
    gather_k<<<4096, 256, 0, stream>>>(embed, (const int*)sent, ws);
    // layer 0
    gemm_k<128><<<4096, 256, 0, stream>>>(x0, (const u16*)(ws + OFF_WIH0), Zb);
    scan_k<<<256, 512, 0, stream>>>(Zb, (const u16*)(ws + OFF_WHH0),
                                    (const float*)(ws + OFF_B0), h0);
    // layer 1
    gemm_k<256><<<4096, 256, 0, stream>>>(h0, (const u16*)(ws + OFF_WIH1), Zb);
    scan_k<<<256, 512, 0, stream>>>(Zb, (const u16*)(ws + OFF_WHH1),
                                    (const float*)(ws + OFF_B1), h1);
    // emissions + CRF
    emis_k<<<256, 256, 0, stream>>>(h1, (const u16*)(ws + OFF_WOUT),
                                    (const float*)(ws + OFF_BOUT), em);
    crf_k<<<192, 64, 0, stream>>>(em, (const int*)tags,
                                  (const float*)(ws + OFF_TRANS),
                                  (const float*)(ws + OFF_START),
                                  (const float*)(ws + OFF_END), part);
    fin_k<<<1, 64, 0, stream>>>(part, d_out, ws);
}

// Round 4
// 1530.680 us; speedup vs baseline: 1.0883x; 1.0060x over previous
//
#include <hip/hip_runtime.h>
#include <hip/hip_bf16.h>
#include <cstddef>

typedef unsigned short u16;
typedef short bf16x8 __attribute__((ext_vector_type(8)));
typedef unsigned short u16x8 __attribute__((ext_vector_type(8)));
typedef float f32x4 __attribute__((ext_vector_type(4)));

constexpr int CB = 128;    // batch
constexpr int CT = 512;    // time
constexpr int CE = 128;    // embed dim
constexpr int CK = 20;     // tags

// ---- workspace layout (bytes) ----
constexpr size_t OFF_FLAG  = 0;                       // int dtype flag (1=bf16 inputs)
constexpr size_t OFF_WIH0  = 256;                     // bf16 [1024][128]
constexpr size_t OFF_WHH0  = OFF_WIH0 + 262144;       // bf16 [1024][128]
constexpr size_t OFF_WIH1  = OFF_WHH0 + 262144;       // bf16 [1024][256]
constexpr size_t OFF_WHH1  = OFF_WIH1 + 524288;       // bf16 [1024][128]
constexpr size_t OFF_WOUT  = OFF_WHH1 + 262144;       // bf16 [20][256]
constexpr size_t OFF_B0    = OFF_WOUT + 10240;        // f32 [1024]
constexpr size_t OFF_B1    = OFF_B0 + 4096;           // f32 [1024]
constexpr size_t OFF_BOUT  = OFF_B1 + 4096;           // f32 [20]
constexpr size_t OFF_TRANS = OFF_BOUT + 256;          // f32 [400]
constexpr size_t OFF_START = OFF_TRANS + 1792;        // f32 [20]
constexpr size_t OFF_END   = OFF_START + 256;         // f32 [20]
constexpr size_t OFF_PART  = OFF_END + 256;           // f32 [256]: logZ[128], score[128]
constexpr size_t OFF_X0    = 2097152;                 // bf16 [65536][128]
constexpr size_t OFF_H0    = OFF_X0 + 16777216;       // bf16 [65536][256]
constexpr size_t OFF_H1    = OFF_H0 + 33554432;       // bf16 [65536][256]
constexpr size_t OFF_EM    = OFF_H1 + 33554432;       // f32  [65536][20]
constexpr size_t OFF_Z     = OFF_EM + 5242880;        // bf16 Z'[(b*2+d)][t][512] (reused L0/L1)
constexpr size_t WS_NEED   = OFF_Z + 134217728;       // ~225.4 MB

__device__ __forceinline__ float b2f(u16 u) {
    union { unsigned int i; float f; } v; v.i = ((unsigned int)u) << 16; return v.f;
}
__device__ __forceinline__ u16 f2b(float f) {
    union { float f; unsigned int i; } v; v.f = f;
    unsigned int r = v.i + 0x7FFFu + ((v.i >> 16) & 1u);   // RNE
    return (u16)(r >> 16);
}
__device__ __forceinline__ float ldin(const void* p, long i, int bf) {
    return bf ? b2f(((const u16*)p)[i]) : ((const float*)p)[i];
}
__device__ __forceinline__ float sigm(float x) { return 1.0f / (1.0f + __expf(-x)); }
__device__ __forceinline__ float tanh_f(float x) { return 2.0f / (1.0f + __expf(-2.0f * x)) - 1.0f; }

// ---- detect whether float inputs are bf16 or f32, from `trans` (400 uniform(-0.1,0.1)) ----
__global__ void sniff_k(const unsigned char* __restrict__ traw, int* __restrict__ flag) {
    int lane = threadIdx.x;
    int votes = 0;
    for (int w = lane; w < 200; w += 64) {
        unsigned char b1 = traw[w * 4 + 1];
        unsigned char e = b1 & 0x7F;
        if (e >= 0x20 && e <= 0x3E) votes++;
    }
    #pragma unroll
    for (int off = 32; off; off >>= 1) votes += __shfl_xor(votes, off);
    if (lane == 0) *flag = (votes > 120) ? 1 : 0;
}

// ---- convert all weights into canonical ws copies (bf16 matrices, f32 vectors) ----
__global__ __launch_bounds__(256) void prep_k(
    const void* wih0, const void* whh0, const void* b0,
    const void* wih1, const void* whh1, const void* b1,
    const void* wout, const void* bout, const void* trans,
    const void* start, const void* end, unsigned char* ws)
{
    const int bf = *(const int*)(ws + OFF_FLAG);
    long tid = (long)blockIdx.x * 256 + threadIdx.x;
    u16* wih0b = (u16*)(ws + OFF_WIH0);
    u16* whh0b = (u16*)(ws + OFF_WHH0);
    u16* wih1b = (u16*)(ws + OFF_WIH1);
    u16* whh1b = (u16*)(ws + OFF_WHH1);
    u16* woutb = (u16*)(ws + OFF_WOUT);
    float* b0f   = (float*)(ws + OFF_B0);
    float* b1f   = (float*)(ws + OFF_B1);
    float* boutf = (float*)(ws + OFF_BOUT);
    float* trf   = (float*)(ws + OFF_TRANS);
    float* stf   = (float*)(ws + OFF_START);
    float* enf   = (float*)(ws + OFF_END);

    if (tid < 131072) { wih0b[tid] = f2b(ldin(wih0, tid, bf)); return; } tid -= 131072;
    if (tid < 131072) { whh0b[tid] = f2b(ldin(whh0, tid, bf)); return; } tid -= 131072;
    if (tid < 1024)   { b0f[tid]   = ldin(b0, tid, bf);        return; } tid -= 1024;
    if (tid < 262144) { wih1b[tid] = f2b(ldin(wih1, tid, bf)); return; } tid -= 262144;
    if (tid < 131072) { whh1b[tid] = f2b(ldin(whh1, tid, bf)); return; } tid -= 131072;
    if (tid < 1024)   { b1f[tid]   = ldin(b1, tid, bf);        return; } tid -= 1024;
    if (tid < 5120)   { woutb[tid] = f2b(ldin(wout, tid, bf)); return; } tid -= 5120;
    if (tid < 20)     { boutf[tid] = ldin(bout, tid, bf);      return; } tid -= 20;
    if (tid < 400)    { trf[tid]   = ldin(trans, tid, bf);     return; } tid -= 400;
    if (tid < 20)     { stf[tid]   = ldin(start, tid, bf);     return; } tid -= 20;
    if (tid < 20)     { enf[tid]   = ldin(end, tid, bf);       return; }
}

// ---- embedding gather -> x0 bf16 [m = t*CB+b][128] ----
__global__ __launch_bounds__(256) void gather_k(const void* __restrict__ embed,
                                                const int* __restrict__ sent,
                                                unsigned char* __restrict__ ws)
{
    const int bf = *(const int*)(ws + OFF_FLAG);
    u16* x0 = (u16*)(ws + OFF_X0);
    int tid = blockIdx.x * 256 + threadIdx.x;      // 1,048,576 threads
    int m = tid >> 4, ch = tid & 15;               // 16 chunks of 8 elems per row
    int t = m >> 7, b = m & 127;
    int s = sent[b * CT + t];
    long src = (long)s * CE + ch * 8;
    u16x8 o;
    if (bf) {
        o = *(const u16x8*)((const u16*)embed + src);
    } else {
        const float* ef = (const float*)embed + src;
        f32x4 lo = *(const f32x4*)ef;
        f32x4 hi = *(const f32x4*)(ef + 4);
        o[0]=f2b(lo[0]); o[1]=f2b(lo[1]); o[2]=f2b(lo[2]); o[3]=f2b(lo[3]);
        o[4]=f2b(hi[0]); o[5]=f2b(hi[1]); o[6]=f2b(hi[2]); o[7]=f2b(hi[3]);
    }
    *(u16x8*)(x0 + (long)m * CE + ch * 8) = o;
}

// ---- bf16 MFMA GEMM: computes A[M,KD] @ B[1024,KD]^T, stores into Z' ----
// Z'[(b*2 + (col>>9))][t][col&511] where input row m = t*CB + b.
template<int KD>
__global__ __launch_bounds__(256) void gemm_k(const u16* __restrict__ A,
                                              const u16* __restrict__ Bw,
                                              u16* __restrict__ Zp)
{
    const int wave = threadIdx.x >> 6, lane = threadIdx.x & 63;
    const int lr = lane & 15, kg = (lane >> 4) * 8;
    const long m0 = (long)blockIdx.x * 16;
    const int n0 = wave * 256;
    const u16* Ap = A + (m0 + lr) * KD + kg;
    const u16* Bp = Bw + (long)(n0 + lr) * KD + kg;
    f32x4 acc[16];
    #pragma unroll
    for (int i = 0; i < 16; ++i) acc[i] = (f32x4){0.f, 0.f, 0.f, 0.f};
    #pragma unroll
    for (int kk = 0; kk < KD; kk += 32) {
        bf16x8 av = *(const bf16x8*)(Ap + kk);
        #pragma unroll
        for (int nt = 0; nt < 16; ++nt) {
            bf16x8 bv = *(const bf16x8*)(Bp + (long)nt * 16 * KD + kk);
            acc[nt] = __builtin_amdgcn_mfma_f32_16x16x32_bf16(av, bv, acc[nt], 0, 0, 0);
        }
    }
    const int rr0 = (lane >> 4) * 4;
    const int t = (int)(m0 >> 7);              // 16 rows of a block share one t
    #pragma unroll
    for (int nt = 0; nt < 16; ++nt) {
        const int col = n0 + nt * 16 + lr;
        const int dd = col >> 9, j = col & 511;
        #pragma unroll
        for (int r = 0; r < 4; ++r) {
            const int bb = (int)((m0 & 127) + rr0 + r);
            Zp[((long)(bb * 2 + dd) * CT + t) * 512 + j] = f2b(acc[nt][r]);
        }
    }
}

// ---- LSTM scan v3: one block per (b,d); 8 waves; wave w owns h rows [w*16,w*16+16) ----
// B-fragments = 4 gate-type tiles (i,f,g,o) x 4 k-tiles of Whh, resident in VGPRs.
// A = h broadcast to all 16 M rows. After 16 MFMAs a lane holds all 4 gate
// pre-activations for h row j0+(lane&15) -> c/h update fully in-register.
// hbuf double-buffered => ONE barrier per step. Z' staged 16 steps at a time
// into LDS (double-buffered, reg-staged issue-early/write-late) so barrier
// vmcnt-drains hit HBM latency once per 16 steps, not every step.
__global__ __launch_bounds__(512, 2) void scan_k(const u16* __restrict__ Zp,
                                                 const u16* __restrict__ Whh,
                                                 const float* __restrict__ bias,
                                                 u16* __restrict__ hout)
{
    const int b = blockIdx.x & 127, d = blockIdx.x >> 7;
    const int tid = threadIdx.x;
    const int lane = tid & 63;
    const int wave = tid >> 6;
    const int lr = lane & 15, kg = (lane >> 4) * 8;
    const int j0 = wave * 16;                    // this wave's h rows

    // B-fragments: bfrag[gt][kt] = Whh[d*512 + gt*128 + j0 + lr][kt*32 + kg .. +7]
    bf16x8 bfrag[4][4];
    const u16* wbase = Whh + (long)(d * 512 + j0 + lr) * 128 + kg;
    #pragma unroll
    for (int gt = 0; gt < 4; ++gt)
        #pragma unroll
        for (int kt = 0; kt < 4; ++kt)
            bfrag[gt][kt] = *(const bf16x8*)(wbase + (long)gt * 128 * 128 + kt * 32);

    float bg[4];
    #pragma unroll
    for (int gt = 0; gt < 4; ++gt) bg[gt] = bias[d * 512 + gt * 128 + j0 + lr];

    __shared__ __align__(16) u16 hbuf[2][128];     // double-buffered h (bf16)
    __shared__ __align__(16) u16 zbuf[2][16][512]; // 16-step Z staging, dbuf (32 KB)
    __shared__ __align__(16) u16 hist[16][128];    // h history for batched flush

    const u16* zseq = Zp + (long)(b * 2 + d) * CT * 512;
    const int u0 = tid >> 6, c8 = (lane) * 8;      // staging coords: row u0/u0+8, 16B col

    // prologue: group 0 into zbuf[0]; h(-1) = 0
    {
        const int ta = d ? (511 - u0) : u0;
        const int tb = d ? (503 - u0) : (u0 + 8);
        u16x8 va = *(const u16x8*)(zseq + (long)ta * 512 + c8);
        u16x8 vb = *(const u16x8*)(zseq + (long)tb * 512 + c8);
        *(u16x8*)&zbuf[0][u0][c8]     = va;
        *(u16x8*)&zbuf[0][u0 + 8][c8] = vb;
    }
    if (tid < 128) hbuf[0][tid] = 0;
    __syncthreads();

    float c = 0.f;
    u16x8 zrA = {}, zrB = {};

    for (int s = 0; s < CT; ++s) {
        const int slot = s & 15, grp = s >> 4;
        if (slot == 0 && grp + 1 < 32) {           // issue next group's loads early
            const int base = (grp + 1) * 16;
            const int ta = d ? (511 - (base + u0)) : (base + u0);
            const int tb = d ? (ta - 8) : (ta + 8);
            zrA = *(const u16x8*)(zseq + (long)ta * 512 + c8);
            zrB = *(const u16x8*)(zseq + (long)tb * 512 + c8);
        }

        // gate pre-activation inputs from staged Z
        const u16* zrow = &zbuf[grp & 1][slot][0];
        float zx[4];
        #pragma unroll
        for (int gt = 0; gt < 4; ++gt) zx[gt] = b2f(zrow[gt * 128 + j0 + lr]);

        // A-fragments: broadcast h (same chunk for every 16-lane group row)
        const u16* hb = &hbuf[s & 1][0];
        bf16x8 av[4];
        #pragma unroll
        for (int kt = 0; kt < 4; ++kt)
            av[kt] = *(const bf16x8*)(hb + kt * 32 + kg);

        f32x4 aa[4], ab[4];
        #pragma unroll
        for (int gt = 0; gt < 4; ++gt) {
            aa[gt] = (f32x4){zx[gt] + bg[gt], 0.f, 0.f, 0.f};  // fold z+bias into C
            ab[gt] = (f32x4){0.f, 0.f, 0.f, 0.f};
        }
        #pragma unroll
        for (int gt = 0; gt < 4; ++gt) {
            aa[gt] = __builtin_amdgcn_mfma_f32_16x16x32_bf16(av[0], bfrag[gt][0], aa[gt], 0, 0, 0);
            ab[gt] = __builtin_amdgcn_mfma_f32_16x16x32_bf16(av[1], bfrag[gt][1], ab[gt], 0, 0, 0);
            aa[gt] = __builtin_amdgcn_mfma_f32_16x16x32_bf16(av[2], bfrag[gt][2], aa[gt], 0, 0, 0);
            ab[gt] = __builtin_amdgcn_mfma_f32_16x16x32_bf16(av[3], bfrag[gt][3], ab[gt], 0, 0, 0);
        }

        const float iv = sigm(aa[0][0] + ab[0][0]);
        const float fv = sigm(aa[1][0] + ab[1][0]);
        const float gv = tanh_f(aa[2][0] + ab[2][0]);
        const float ov = sigm(aa[3][0] + ab[3][0]);
        c = fmaf(fv, c, iv * gv);
        const float h = ov * tanh_f(c);
        const u16 hv16 = f2b(h);
        if (lane < 16) {
            hbuf[(s + 1) & 1][j0 + lr] = hv16;
            hist[slot][j0 + lr] = hv16;
        }

        if (slot == 15) {
            if (grp + 1 < 32) {                    // stage next group into other buffer
                *(u16x8*)&zbuf[(grp + 1) & 1][u0][c8]     = zrA;
                *(u16x8*)&zbuf[(grp + 1) & 1][u0 + 8][c8] = zrB;
            }
            __syncthreads();                        // hist complete; zbuf written; h ready
            if (tid < 256) {                        // flush 16 steps of h
                const int u = tid >> 4, cc = (tid & 15) * 8;
                const int tu = d ? (511 - (grp * 16 + u)) : (grp * 16 + u);
                *(u16x8*)(hout + ((long)tu * CB + b) * 256 + d * 128 + cc) =
                    *(const u16x8*)&hist[u][cc];
            }
            __syncthreads();                        // hist free before slot 0 rewrites
        } else {
            __syncthreads();
        }
    }
}

// ---- emissions: em[m][20] = h1[m] @ Wout^T + bout (f32) ----
__global__ __launch_bounds__(256) void emis_k(const u16* __restrict__ h1,
                                              const u16* __restrict__ woutb,
                                              const float* __restrict__ boutf,
                                              float* __restrict__ em)
{
    __shared__ __align__(16) float wsm[CK * 256];
    for (int i = threadIdx.x; i < CK * 256; i += 256) wsm[i] = b2f(woutb[i]);
    __syncthreads();
    const long m = (long)blockIdx.x * 256 + threadIdx.x;
    const u16* hrow = h1 + m * 256;
    float acc[CK];
    #pragma unroll
    for (int n = 0; n < CK; ++n) acc[n] = boutf[n];
    for (int k8 = 0; k8 < 32; ++k8) {
        u16x8 u = *(const u16x8*)(hrow + k8 * 8);
        float hv[8];
        #pragma unroll
        for (int j = 0; j < 8; ++j) hv[j] = b2f(u[j]);
        #pragma unroll
        for (int n = 0; n < CK; ++n) {
            const f32x4 w0 = *(const f32x4*)&wsm[n * 256 + k8 * 8];
            const f32x4 w1 = *(const f32x4*)&wsm[n * 256 + k8 * 8 + 4];
            acc[n] = fmaf(hv[0], w0[0], acc[n]); acc[n] = fmaf(hv[1], w0[1], acc[n]);
            acc[n] = fmaf(hv[2], w0[2], acc[n]); acc[n] = fmaf(hv[3], w0[3], acc[n]);
            acc[n] = fmaf(hv[4], w1[0], acc[n]); acc[n] = fmaf(hv[5], w1[1], acc[n]);
            acc[n] = fmaf(hv[6], w1[2], acc[n]); acc[n] = fmaf(hv[7], w1[3], acc[n]);
        }
    }
    float* emrow = em + m * CK;
    #pragma unroll
    for (int n = 0; n < CK; ++n) emrow[n] = acc[n];
}

// ---- CRF ----
__global__ void crf_k(const float* __restrict__ em, const int* __restrict__ tags,
                      const float* __restrict__ trf, const float* __restrict__ stf,
                      const float* __restrict__ enf, float* __restrict__ partial)
{
    const int lane = threadIdx.x;      // 64
    if (blockIdx.x < 64) {
        const int j = lane & 31, half = lane >> 5;
        const int b = blockIdx.x * 2 + half;
        const bool act = j < CK;
        float tcol[CK];
        #pragma unroll
        for (int i = 0; i < CK; ++i) tcol[i] = act ? trf[i * CK + j] : 0.f;
        float alpha = act ? (stf[j] + em[(long)b * CK + j]) : -1e30f;
        for (int t = 1; t < CT; ++t) {
            float v[CK];
            #pragma unroll
            for (int i = 0; i < CK; ++i)
                v[i] = __shfl(alpha, i, 32) + tcol[i];
            float m1[10], m2[5];
            #pragma unroll
            for (int i = 0; i < 10; ++i) m1[i] = fmaxf(v[2 * i], v[2 * i + 1]);
            #pragma unroll
            for (int i = 0; i < 5; ++i) m2[i] = fmaxf(m1[2 * i], m1[2 * i + 1]);
            const float mx = fmaxf(fmaxf(fmaxf(m2[0], m2[1]), fmaxf(m2[2], m2[3])), m2[4]);
            float e[CK];
            #pragma unroll
            for (int i = 0; i < CK; ++i) e[i] = __expf(v[i] - mx);
            float s1[10], s2[5];
            #pragma unroll
            for (int i = 0; i < 10; ++i) s1[i] = e[2 * i] + e[2 * i + 1];
            #pragma unroll
            for (int i = 0; i < 5; ++i) s2[i] = s1[2 * i] + s1[2 * i + 1];
            const float s = (s2[0] + s2[1]) + (s2[2] + s2[3]) + s2[4];
            const float emv = act ? em[((long)t * CB + b) * CK + j] : 0.f;
            const float na = mx + __logf(s) + emv;
            alpha = act ? na : -1e30f;
        }
        float vv = act ? (alpha + enf[j]) : -1e30f;
        float mx = vv;
        #pragma unroll
        for (int off = 16; off; off >>= 1) mx = fmaxf(mx, __shfl_xor(mx, off, 32));
        float ex = act ? __expf(vv - mx) : 0.f;
        #pragma unroll
        for (int off = 16; off; off >>= 1) ex += __shfl_xor(ex, off, 32);
        if (j == 0) partial[b] = mx + __logf(ex);
    } else {
        const int b = blockIdx.x - 64;
        float sc = 0.f;
        for (int t = lane; t < CT; t += 64) {
            const int tg = tags[b * CT + t];
            sc += em[((long)t * CB + b) * CK + tg];
            if (t >= 1) sc += trf[tags[b * CT + t - 1] * CK + tg];
        }
        #pragma unroll
        for (int off = 32; off; off >>= 1) sc += __shfl_xor(sc, off);
        if (lane == 0)
            partial[128 + b] = sc + stf[tags[b * CT]] + enf[tags[b * CT + CT - 1]];
    }
}

__global__ void fin_k(const float* __restrict__ partial, void* __restrict__ out,
                      const unsigned char* __restrict__ ws)
{
    const int bf = *(const int*)(ws + OFF_FLAG);
    const int lane = threadIdx.x;  // 64
    float v = (partial[lane] - partial[128 + lane]) + (partial[lane + 64] - partial[192 + lane]);
    #pragma unroll
    for (int off = 32; off; off >>= 1) v += __shfl_xor(v, off);
    if (lane == 0) {
        const float mean = v / 128.f;
        if (bf) ((u16*)out)[0] = f2b(mean);
        else    ((float*)out)[0] = mean;
    }
}

extern "C" void kernel_launch(void* const* d_in, const int* in_sizes, int n_in,
                              void* d_out, int out_size, void* d_ws, size_t ws_size,
                              hipStream_t stream) {
    (void)in_sizes; (void)n_in; (void)out_size;
    if (ws_size < WS_NEED) return;
    unsigned char* ws = (unsigned char*)d_ws;

    const void* sent  = d_in[0];
    const void* tags  = d_in[1];
    const void* embed = d_in[3];

    u16* x0  = (u16*)(ws + OFF_X0);
    u16* h0  = (u16*)(ws + OFF_H0);
    u16* h1  = (u16*)(ws + OFF_H1);
    u16* Zb  = (u16*)(ws + OFF_Z);
    float* em = (float*)(ws + OFF_EM);
    float* part = (float*)(ws + OFF_PART);

    sniff_k<<<1, 64, 0, stream>>>((const unsigned char*)d_in[12], (int*)(ws + OFF_FLAG));
    prep_k<<<2590, 256, 0, stream>>>(d_in[4], d_in[5], d_in[6], d_in[7], d_in[8],
                                     d_in[9], d_in[10], d_in[11], d_in[12], d_in[13],
                                     d_in[14], ws);
    gather_k<<<4096, 256, 0, stream>>>(embed, (const int*)sent, ws);
    // layer 0
    gemm_k<128><<<4096, 256, 0, stream>>>(x0, (const u16*)(ws + OFF_WIH0), Zb);
    scan_k<<<256, 512, 0, stream>>>(Zb, (const u16*)(ws + OFF_WHH0),
                                    (const float*)(ws + OFF_B0), h0);
    // layer 1
    gemm_k<256><<<4096, 256, 0, stream>>>(h0, (const u16*)(ws + OFF_WIH1), Zb);
    scan_k<<<256, 512, 0, stream>>>(Zb, (const u16*)(ws + OFF_WHH1),
                                    (const float*)(ws + OFF_B1), h1);
    // emissions + CRF
    emis_k<<<256, 256, 0, stream>>>(h1, (const u16*)(ws + OFF_WOUT),
                                    (const float*)(ws + OFF_BOUT), em);
    crf_k<<<192, 64, 0, stream>>>(em, (const int*)tags,
                                  (const float*)(ws + OFF_TRANS),
                                  (const float*)(ws + OFF_START),
                                  (const float*)(ws + OFF_END), part);
    fin_k<<<1, 64, 0, stream>>>(part, d_out, ws);
}

// Round 5
// 1482.571 us; speedup vs baseline: 1.1237x; 1.0324x over previous
//
#include <hip/hip_runtime.h>
#include <hip/hip_bf16.h>
#include <cstddef>

typedef unsigned short u16;
typedef short bf16x8 __attribute__((ext_vector_type(8)));
typedef unsigned short u16x8 __attribute__((ext_vector_type(8)));
typedef unsigned short u16x4 __attribute__((ext_vector_type(4)));
typedef float f32x4 __attribute__((ext_vector_type(4)));

constexpr int CB = 128;    // batch
constexpr int CT = 512;    // time
constexpr int CE = 128;    // embed dim
constexpr int CK = 20;     // tags

// ---- workspace layout (bytes) ----
constexpr size_t OFF_FLAG  = 0;                       // int dtype flag (1=bf16 inputs)
constexpr size_t OFF_WIH0  = 256;                     // bf16 [1024][128]
constexpr size_t OFF_WHH0  = OFF_WIH0 + 262144;       // bf16 [1024][128]
constexpr size_t OFF_WIH1  = OFF_WHH0 + 262144;       // bf16 [1024][256]
constexpr size_t OFF_WHH1  = OFF_WIH1 + 524288;       // bf16 [1024][128]
constexpr size_t OFF_WOUT  = OFF_WHH1 + 262144;       // bf16 [20][256]
constexpr size_t OFF_B0    = OFF_WOUT + 10240;        // f32 [1024]
constexpr size_t OFF_B1    = OFF_B0 + 4096;           // f32 [1024]
constexpr size_t OFF_BOUT  = OFF_B1 + 4096;           // f32 [20]
constexpr size_t OFF_TRANS = OFF_BOUT + 256;          // f32 [400]
constexpr size_t OFF_START = OFF_TRANS + 1792;        // f32 [20]
constexpr size_t OFF_END   = OFF_START + 256;         // f32 [20]
constexpr size_t OFF_PART  = OFF_END + 256;           // f32 [256]: logZ[128], score[128]
constexpr size_t OFF_X0    = 2097152;                 // bf16 [65536][128]
constexpr size_t OFF_H0    = OFF_X0 + 16777216;       // bf16 [65536][256]
constexpr size_t OFF_H1    = OFF_H0 + 33554432;       // bf16 [65536][256]
constexpr size_t OFF_EM    = OFF_H1 + 33554432;       // f32  [65536][20]
constexpr size_t OFF_Z     = OFF_EM + 5242880;        // bf16 Z''[(b*2+d)][t][flat=row*4+gt]
constexpr size_t WS_NEED   = OFF_Z + 134217728;       // ~225.4 MB

__device__ __forceinline__ float b2f(u16 u) {
    union { unsigned int i; float f; } v; v.i = ((unsigned int)u) << 16; return v.f;
}
__device__ __forceinline__ u16 f2b(float f) {
    union { float f; unsigned int i; } v; v.f = f;
    unsigned int r = v.i + 0x7FFFu + ((v.i >> 16) & 1u);   // RNE
    return (u16)(r >> 16);
}
__device__ __forceinline__ float ldin(const void* p, long i, int bf) {
    return bf ? b2f(((const u16*)p)[i]) : ((const float*)p)[i];
}
__device__ __forceinline__ float sigm(float x) { return 1.0f / (1.0f + __expf(-x)); }
__device__ __forceinline__ float tanh_f(float x) { return 2.0f / (1.0f + __expf(-2.0f * x)) - 1.0f; }

// ---- detect whether float inputs are bf16 or f32, from `trans` (400 uniform(-0.1,0.1)) ----
__global__ void sniff_k(const unsigned char* __restrict__ traw, int* __restrict__ flag) {
    int lane = threadIdx.x;
    int votes = 0;
    for (int w = lane; w < 200; w += 64) {
        unsigned char b1 = traw[w * 4 + 1];
        unsigned char e = b1 & 0x7F;
        if (e >= 0x20 && e <= 0x3E) votes++;
    }
    #pragma unroll
    for (int off = 32; off; off >>= 1) votes += __shfl_xor(votes, off);
    if (lane == 0) *flag = (votes > 120) ? 1 : 0;
}

// ---- convert all weights into canonical ws copies (bf16 matrices, f32 vectors) ----
__global__ __launch_bounds__(256) void prep_k(
    const void* wih0, const void* whh0, const void* b0,
    const void* wih1, const void* whh1, const void* b1,
    const void* wout, const void* bout, const void* trans,
    const void* start, const void* end, unsigned char* ws)
{
    const int bf = *(const int*)(ws + OFF_FLAG);
    long tid = (long)blockIdx.x * 256 + threadIdx.x;
    u16* wih0b = (u16*)(ws + OFF_WIH0);
    u16* whh0b = (u16*)(ws + OFF_WHH0);
    u16* wih1b = (u16*)(ws + OFF_WIH1);
    u16* whh1b = (u16*)(ws + OFF_WHH1);
    u16* woutb = (u16*)(ws + OFF_WOUT);
    float* b0f   = (float*)(ws + OFF_B0);
    float* b1f   = (float*)(ws + OFF_B1);
    float* boutf = (float*)(ws + OFF_BOUT);
    float* trf   = (float*)(ws + OFF_TRANS);
    float* stf   = (float*)(ws + OFF_START);
    float* enf   = (float*)(ws + OFF_END);

    if (tid < 131072) { wih0b[tid] = f2b(ldin(wih0, tid, bf)); return; } tid -= 131072;
    if (tid < 131072) { whh0b[tid] = f2b(ldin(whh0, tid, bf)); return; } tid -= 131072;
    if (tid < 1024)   { b0f[tid]   = ldin(b0, tid, bf);        return; } tid -= 1024;
    if (tid < 262144) { wih1b[tid] = f2b(ldin(wih1, tid, bf)); return; } tid -= 262144;
    if (tid < 131072) { whh1b[tid] = f2b(ldin(whh1, tid, bf)); return; } tid -= 131072;
    if (tid < 1024)   { b1f[tid]   = ldin(b1, tid, bf);        return; } tid -= 1024;
    if (tid < 5120)   { woutb[tid] = f2b(ldin(wout, tid, bf)); return; } tid -= 5120;
    if (tid < 20)     { boutf[tid] = ldin(bout, tid, bf);      return; } tid -= 20;
    if (tid < 400)    { trf[tid]   = ldin(trans, tid, bf);     return; } tid -= 400;
    if (tid < 20)     { stf[tid]   = ldin(start, tid, bf);     return; } tid -= 20;
    if (tid < 20)     { enf[tid]   = ldin(end, tid, bf);       return; }
}

// ---- embedding gather -> x0 bf16 [m = t*CB+b][128] ----
__global__ __launch_bounds__(256) void gather_k(const void* __restrict__ embed,
                                                const int* __restrict__ sent,
                                                unsigned char* __restrict__ ws)
{
    const int bf = *(const int*)(ws + OFF_FLAG);
    u16* x0 = (u16*)(ws + OFF_X0);
    int tid = blockIdx.x * 256 + threadIdx.x;      // 1,048,576 threads
    int m = tid >> 4, ch = tid & 15;               // 16 chunks of 8 elems per row
    int t = m >> 7, b = m & 127;
    int s = sent[b * CT + t];
    long src = (long)s * CE + ch * 8;
    u16x8 o;
    if (bf) {
        o = *(const u16x8*)((const u16*)embed + src);
    } else {
        const float* ef = (const float*)embed + src;
        f32x4 lo = *(const f32x4*)ef;
        f32x4 hi = *(const f32x4*)(ef + 4);
        o[0]=f2b(lo[0]); o[1]=f2b(lo[1]); o[2]=f2b(lo[2]); o[3]=f2b(lo[3]);
        o[4]=f2b(hi[0]); o[5]=f2b(hi[1]); o[6]=f2b(hi[2]); o[7]=f2b(hi[3]);
    }
    *(u16x8*)(x0 + (long)m * CE + ch * 8) = o;
}

// ---- bf16 MFMA GEMM: A[M,KD] @ B[1024,KD]^T -> Z'' gate-interleaved ----
// Z''[(b*2+dd)][t][row*4+gt]  where col = dd*512 + gt*128 + row,  m = t*CB + b.
template<int KD>
__global__ __launch_bounds__(256) void gemm_k(const u16* __restrict__ A,
                                              const u16* __restrict__ Bw,
                                              u16* __restrict__ Zp)
{
    const int wave = threadIdx.x >> 6, lane = threadIdx.x & 63;
    const int lr = lane & 15, kg = (lane >> 4) * 8;
    const long m0 = (long)blockIdx.x * 16;
    const int n0 = wave * 256;
    const u16* Ap = A + (m0 + lr) * KD + kg;
    const u16* Bp = Bw + (long)(n0 + lr) * KD + kg;
    f32x4 acc[16];
    #pragma unroll
    for (int i = 0; i < 16; ++i) acc[i] = (f32x4){0.f, 0.f, 0.f, 0.f};
    #pragma unroll
    for (int kk = 0; kk < KD; kk += 32) {
        bf16x8 av = *(const bf16x8*)(Ap + kk);
        #pragma unroll
        for (int nt = 0; nt < 16; ++nt) {
            bf16x8 bv = *(const bf16x8*)(Bp + (long)nt * 16 * KD + kk);
            acc[nt] = __builtin_amdgcn_mfma_f32_16x16x32_bf16(av, bv, acc[nt], 0, 0, 0);
        }
    }
    const int rr0 = (lane >> 4) * 4;
    const int t = (int)(m0 >> 7);              // 16 rows of a block share one t
    #pragma unroll
    for (int nt = 0; nt < 16; ++nt) {
        const int col = n0 + nt * 16 + lr;
        const int dd = col >> 9, cc = col & 511;
        const int gt = cc >> 7, row = cc & 127;
        const int flat = row * 4 + gt;
        #pragma unroll
        for (int r = 0; r < 4; ++r) {
            const int bb = (int)((m0 & 127) + rr0 + r);
            Zp[((long)(bb * 2 + dd) * CT + t) * 512 + flat] = f2b(acc[nt][r]);
        }
    }
}

// ---- LSTM scan v4: one block per (b,d); 8 waves; wave w owns h rows [w*16,w*16+16) ----
// bfrag (Whh) resident in regs. acc = 4 depth-4 MFMA chains (16 regs).
// zx = single ds_read_b64 (gate-interleaved Z''). Barriers are lgkm-only
// (inline asm) so global prefetch loads stay in flight across steps and
// the direct hout stores never get drained.
__global__ __launch_bounds__(512, 2) void scan_k(const u16* __restrict__ Zp,
                                                 const u16* __restrict__ Whh,
                                                 const float* __restrict__ bias,
                                                 u16* __restrict__ hout)
{
    const int b = blockIdx.x & 127, d = blockIdx.x >> 7;
    const int tid = threadIdx.x;
    const int lane = tid & 63;
    const int wave = tid >> 6;
    const int lr = lane & 15, kg = (lane >> 4) * 8;
    const int row = wave * 16 + lr;              // this lane's h row

    // B-fragments: bfrag[gt][kt] = Whh[d*512 + gt*128 + row][kt*32 + kg .. +7]
    bf16x8 bfrag[4][4];
    const u16* wbase = Whh + (long)(d * 512 + row) * 128 + kg;
    #pragma unroll
    for (int gt = 0; gt < 4; ++gt)
        #pragma unroll
        for (int kt = 0; kt < 4; ++kt)
            bfrag[gt][kt] = *(const bf16x8*)(wbase + (long)gt * 128 * 128 + kt * 32);

    float bgv[4];
    #pragma unroll
    for (int gt = 0; gt < 4; ++gt) bgv[gt] = bias[d * 512 + gt * 128 + row];

    __shared__ __align__(16) u16 hbuf[2][128];     // double-buffered h (bf16)
    __shared__ __align__(16) u16 zbuf[2][16][512]; // 16-step Z staging, dbuf (32 KB)

    const u16* zseq = Zp + (long)(b * 2 + d) * CT * 512;

    // prologue: stage group 0; issue group 1 loads (left in flight)
    {
        const long g0 = d ? (long)496 * 512 : 0;
        u16x8 p0 = *(const u16x8*)(zseq + g0 + tid * 8);
        u16x8 p1 = *(const u16x8*)(zseq + g0 + 4096 + tid * 8);
        *(u16x8*)(&zbuf[0][0][0] + tid * 8) = p0;
        *(u16x8*)(&zbuf[0][0][0] + 4096 + tid * 8) = p1;
    }
    u16x8 zrA, zrB;
    {
        const long g1 = d ? (long)480 * 512 : (long)16 * 512;
        zrA = *(const u16x8*)(zseq + g1 + tid * 8);
        zrB = *(const u16x8*)(zseq + g1 + 4096 + tid * 8);
    }
    if (tid < 128) hbuf[0][tid] = 0;
    asm volatile("s_waitcnt lgkmcnt(0)\n\ts_barrier" ::: "memory");

    float c = 0.f;
    for (int s = 0; s < CT; ++s) {
        const int slot = s & 15, grp = s >> 4;
        if (slot == 0 && grp > 0 && grp + 1 < 32) {   // refill prefetch regs (15-step flight)
            const long gb = d ? (long)(496 - (grp + 1) * 16) * 512
                              : (long)(grp + 1) * 16 * 512;
            zrA = *(const u16x8*)(zseq + gb + tid * 8);
            zrB = *(const u16x8*)(zseq + gb + 4096 + tid * 8);
        }

        // packed gate pre-activations for this lane's row: one b64
        const int zri = d ? (15 - slot) : slot;
        const u16x4 zv = *(const u16x4*)(&zbuf[grp & 1][zri][0] + row * 4);

        // A-fragments: broadcast h (identical for all 16 rows)
        const u16* hb = &hbuf[s & 1][0];
        const bf16x8 av0 = *(const bf16x8*)(hb + 0 * 32 + kg);
        const bf16x8 av1 = *(const bf16x8*)(hb + 1 * 32 + kg);
        const bf16x8 av2 = *(const bf16x8*)(hb + 2 * 32 + kg);
        const bf16x8 av3 = *(const bf16x8*)(hb + 3 * 32 + kg);

        f32x4 acc[4];
        #pragma unroll
        for (int gt = 0; gt < 4; ++gt) acc[gt] = (f32x4){0.f, 0.f, 0.f, 0.f};
        #pragma unroll
        for (int gt = 0; gt < 4; ++gt)
            acc[gt] = __builtin_amdgcn_mfma_f32_16x16x32_bf16(av0, bfrag[gt][0], acc[gt], 0, 0, 0);
        #pragma unroll
        for (int gt = 0; gt < 4; ++gt)
            acc[gt] = __builtin_amdgcn_mfma_f32_16x16x32_bf16(av1, bfrag[gt][1], acc[gt], 0, 0, 0);
        #pragma unroll
        for (int gt = 0; gt < 4; ++gt)
            acc[gt] = __builtin_amdgcn_mfma_f32_16x16x32_bf16(av2, bfrag[gt][2], acc[gt], 0, 0, 0);
        #pragma unroll
        for (int gt = 0; gt < 4; ++gt)
            acc[gt] = __builtin_amdgcn_mfma_f32_16x16x32_bf16(av3, bfrag[gt][3], acc[gt], 0, 0, 0);

        const float iv = sigm(acc[0][0] + (b2f(zv[0]) + bgv[0]));
        const float fv = sigm(acc[1][0] + (b2f(zv[1]) + bgv[1]));
        const float gv = tanh_f(acc[2][0] + (b2f(zv[2]) + bgv[2]));
        const float ov = sigm(acc[3][0] + (b2f(zv[3]) + bgv[3]));
        c = fmaf(fv, c, iv * gv);
        const float h = ov * tanh_f(c);

        if (slot == 15 && grp + 1 < 32) {            // commit prefetched group to LDS
            *(u16x8*)(&zbuf[(grp + 1) & 1][0][0] + tid * 8) = zrA;
            *(u16x8*)(&zbuf[(grp + 1) & 1][0][0] + 4096 + tid * 8) = zrB;
        }
        if (lane < 16) {
            const u16 hv16 = f2b(h);
            hbuf[(s + 1) & 1][row] = hv16;
            const int t = d ? (CT - 1 - s) : s;
            hout[((long)t * CB + b) * 256 + d * 128 + row] = hv16;  // fire-and-forget
        }
        asm volatile("s_waitcnt lgkmcnt(0)\n\ts_barrier" ::: "memory");
    }
}

// ---- emissions: em[m][20] = h1[m] @ Wout^T + bout (f32) ----
__global__ __launch_bounds__(256) void emis_k(const u16* __restrict__ h1,
                                              const u16* __restrict__ woutb,
                                              const float* __restrict__ boutf,
                                              float* __restrict__ em)
{
    __shared__ __align__(16) float wsm[CK * 256];
    for (int i = threadIdx.x; i < CK * 256; i += 256) wsm[i] = b2f(woutb[i]);
    __syncthreads();
    const long m = (long)blockIdx.x * 256 + threadIdx.x;
    const u16* hrow = h1 + m * 256;
    float acc[CK];
    #pragma unroll
    for (int n = 0; n < CK; ++n) acc[n] = boutf[n];
    for (int k8 = 0; k8 < 32; ++k8) {
        u16x8 u = *(const u16x8*)(hrow + k8 * 8);
        float hv[8];
        #pragma unroll
        for (int j = 0; j < 8; ++j) hv[j] = b2f(u[j]);
        #pragma unroll
        for (int n = 0; n < CK; ++n) {
            const f32x4 w0 = *(const f32x4*)&wsm[n * 256 + k8 * 8];
            const f32x4 w1 = *(const f32x4*)&wsm[n * 256 + k8 * 8 + 4];
            acc[n] = fmaf(hv[0], w0[0], acc[n]); acc[n] = fmaf(hv[1], w0[1], acc[n]);
            acc[n] = fmaf(hv[2], w0[2], acc[n]); acc[n] = fmaf(hv[3], w0[3], acc[n]);
            acc[n] = fmaf(hv[4], w1[0], acc[n]); acc[n] = fmaf(hv[5], w1[1], acc[n]);
            acc[n] = fmaf(hv[6], w1[2], acc[n]); acc[n] = fmaf(hv[7], w1[3], acc[n]);
        }
    }
    float* emrow = em + m * CK;
    #pragma unroll
    for (int n = 0; n < CK; ++n) emrow[n] = acc[n];
}

// ---- CRF ----
__global__ void crf_k(const float* __restrict__ em, const int* __restrict__ tags,
                      const float* __restrict__ trf, const float* __restrict__ stf,
                      const float* __restrict__ enf, float* __restrict__ partial)
{
    const int lane = threadIdx.x;      // 64
    if (blockIdx.x < 64) {
        const int j = lane & 31, half = lane >> 5;
        const int b = blockIdx.x * 2 + half;
        const bool act = j < CK;
        float tcol[CK];
        #pragma unroll
        for (int i = 0; i < CK; ++i) tcol[i] = act ? trf[i * CK + j] : 0.f;
        float alpha = act ? (stf[j] + em[(long)b * CK + j]) : -1e30f;
        for (int t = 1; t < CT; ++t) {
            float v[CK];
            #pragma unroll
            for (int i = 0; i < CK; ++i)
                v[i] = __shfl(alpha, i, 32) + tcol[i];
            float m1[10], m2[5];
            #pragma unroll
            for (int i = 0; i < 10; ++i) m1[i] = fmaxf(v[2 * i], v[2 * i + 1]);
            #pragma unroll
            for (int i = 0; i < 5; ++i) m2[i] = fmaxf(m1[2 * i], m1[2 * i + 1]);
            const float mx = fmaxf(fmaxf(fmaxf(m2[0], m2[1]), fmaxf(m2[2], m2[3])), m2[4]);
            float e[CK];
            #pragma unroll
            for (int i = 0; i < CK; ++i) e[i] = __expf(v[i] - mx);
            float s1[10], s2[5];
            #pragma unroll
            for (int i = 0; i < 10; ++i) s1[i] = e[2 * i] + e[2 * i + 1];
            #pragma unroll
            for (int i = 0; i < 5; ++i) s2[i] = s1[2 * i] + s1[2 * i + 1];
            const float s = (s2[0] + s2[1]) + (s2[2] + s2[3]) + s2[4];
            const float emv = act ? em[((long)t * CB + b) * CK + j] : 0.f;
            const float na = mx + __logf(s) + emv;
            alpha = act ? na : -1e30f;
        }
        float vv = act ? (alpha + enf[j]) : -1e30f;
        float mx = vv;
        #pragma unroll
        for (int off = 16; off; off >>= 1) mx = fmaxf(mx, __shfl_xor(mx, off, 32));
        float ex = act ? __expf(vv - mx) : 0.f;
        #pragma unroll
        for (int off = 16; off; off >>= 1) ex += __shfl_xor(ex, off, 32);
        if (j == 0) partial[b] = mx + __logf(ex);
    } else {
        const int b = blockIdx.x - 64;
        float sc = 0.f;
        for (int t = lane; t < CT; t += 64) {
            const int tg = tags[b * CT + t];
            sc += em[((long)t * CB + b) * CK + tg];
            if (t >= 1) sc += trf[tags[b * CT + t - 1] * CK + tg];
        }
        #pragma unroll
        for (int off = 32; off; off >>= 1) sc += __shfl_xor(sc, off);
        if (lane == 0)
            partial[128 + b] = sc + stf[tags[b * CT]] + enf[tags[b * CT + CT - 1]];
    }
}

__global__ void fin_k(const float* __restrict__ partial, void* __restrict__ out,
                      const unsigned char* __restrict__ ws)
{
    const int bf = *(const int*)(ws + OFF_FLAG);
    const int lane = threadIdx.x;  // 64
    float v = (partial[lane] - partial[128 + lane]) + (partial[lane + 64] - partial[192 + lane]);
    #pragma unroll
    for (int off = 32; off; off >>= 1) v += __shfl_xor(v, off);
    if (lane == 0) {
        const float mean = v / 128.f;
        if (bf) ((u16*)out)[0] = f2b(mean);
        else    ((float*)out)[0] = mean;
    }
}

extern "C" void kernel_launch(void* const* d_in, const int* in_sizes, int n_in,
                              void* d_out, int out_size, void* d_ws, size_t ws_size,
                              hipStream_t stream) {
    (void)in_sizes; (void)n_in; (void)out_size;
    if (ws_size < WS_NEED) return;
    unsigned char* ws = (unsigned char*)d_ws;

    const void* sent  = d_in[0];
    const void* tags  = d_in[1];
    const void* embed = d_in[3];

    u16* x0  = (u16*)(ws + OFF_X0);
    u16* h0  = (u16*)(ws + OFF_H0);
    u16* h1  = (u16*)(ws + OFF_H1);
    u16* Zb  = (u16*)(ws + OFF_Z);
    float* em = (float*)(ws + OFF_EM);
    float* part = (float*)(ws + OFF_PART);

    sniff_k<<<1, 64, 0, stream>>>((const unsigned char*)d_in[12], (int*)(ws + OFF_FLAG));
    prep_k<<<2590, 256, 0, stream>>>(d_in[4], d_in[5], d_in[6], d_in[7], d_in[8],
                                     d_in[9], d_in[10], d_in[11], d_in[12], d_in[13],
                                     d_in[14], ws);
    gather_k<<<4096, 256, 0, stream>>>(embed, (const int*)sent, ws);
    // layer 0
    gemm_k<128><<<4096, 256, 0, stream>>>(x0, (const u16*)(ws + OFF_WIH0), Zb);
    scan_k<<<256, 512, 0, stream>>>(Zb, (const u16*)(ws + OFF_WHH0),
                                    (const float*)(ws + OFF_B0), h0);
    // layer 1
    gemm_k<256><<<4096, 256, 0, stream>>>(h0, (const u16*)(ws + OFF_WIH1), Zb);
    scan_k<<<256, 512, 0, stream>>>(Zb, (const u16*)(ws + OFF_WHH1),
                                    (const float*)(ws + OFF_B1), h1);
    // emissions + CRF
    emis_k<<<256, 256, 0, stream>>>(h1, (const u16*)(ws + OFF_WOUT),
                                    (const float*)(ws + OFF_BOUT), em);
    crf_k<<<192, 64, 0, stream>>>(em, (const int*)tags,
                                  (const float*)(ws + OFF_TRANS),
                                  (const float*)(ws + OFF_START),
                                  (const float*)(ws + OFF_END), part);
    fin_k<<<1, 64, 0, stream>>>(part, d_out, ws);
}